// Round 6
// baseline (1778.049 us; speedup 1.0000x reference)
//
#include <hip/hip_runtime.h>
#include <math.h>

// B=64, T=1000, S=96, A=32, INP=128, H=256. All I/O fp32.
// d_ws layout:
//   pre_perm fp16 [8000 slabs][4096 halves] = 65,536,000 B   (slab=(br*4+G)*1000+t)
//   h_perm   fp16 same layout              = 65,536,000 B
//   G3 f16 W_hh B-frag table (262,144 B) at d_ws+130,416,640  (tail of h region)
//   G1/G2 bf16 frag tables  (393,216 B) at d_ws+130,678,784  (tail of h region)
// Tail tables are consumed at ff/rnn START; rnn's h writes only reach those
// bytes at t>=920 of slab-group (br=1,G=3) — hundreds of µs later.
// Permuted value layout (verified by R4 pass): value (br,b,t,col) with
//   G=b>>4, g2=(b>>2)&3, rr=b&3, WV=col>>6, TL=(col>>4)&3, m=col&15 lives at
//   half-index slab*4096 + WV*1024 + g2*256 + m*16 + rr*4 + TL.

typedef _Float16 half2_t __attribute__((ext_vector_type(2)));
typedef _Float16 f16x8   __attribute__((ext_vector_type(8)));    // 4 VGPRs
typedef _Float16 f16x16  __attribute__((ext_vector_type(16)));   // 8 VGPRs
typedef __attribute__((ext_vector_type(8))) short bf16x8;
typedef __attribute__((ext_vector_type(4))) float f32x4;

__device__ __forceinline__ float fdot2(half2_t a, half2_t b, float c) {
#if __has_builtin(__builtin_amdgcn_fdot2)
    return __builtin_amdgcn_fdot2(a, b, c, false);
#else
    return c + (float)a[0] * (float)b[0] + (float)a[1] * (float)b[1];
#endif
}

__device__ __forceinline__ short f2bf(float f) {     // fp32 -> bf16 (RNE)
    unsigned u = __builtin_bit_cast(unsigned, f);
    return (short)((u + 0x7FFFu + ((u >> 16) & 1u)) >> 16);
}

__device__ __forceinline__ void barrier_lds() {
    __asm__ __volatile__("s_waitcnt lgkmcnt(0)" ::: "memory");
    __builtin_amdgcn_s_barrier();
}

// ---------------------------------------------------------------------------
// Kernel 0: pre-swizzle weights into MFMA B-fragment tables.
// G1 (bf16, ff GEMM1): e in [0,8192)
// G2 (bf16, ff GEMM2): e in [8192,24576)
// G3 (f16, rnn W_hh) : e in [24576,40960): ((br*16+nt)*8+ks)*64+lane
// ---------------------------------------------------------------------------
__global__ __launch_bounds__(256, 1)
void prep_kernel(const float* __restrict__ fc11_w, const float* __restrict__ W_ih1,
                 const float* __restrict__ fc21_w, const float* __restrict__ W_ih2,
                 const float* __restrict__ W_hh1, const float* __restrict__ W_hh2,
                 short* __restrict__ tab, _Float16* __restrict__ tab3)
{
    const int e    = blockIdx.x * 256 + threadIdx.x;   // 160*256 = 40960
    const int lane = e & 63;
    const int q = lane >> 4, m = lane & 15;
    if (e < 24576) {
        const float* W;
        int k0, n;
        if (e < 8192) {                       // G1
            int t_ = e >> 6;
            int ks = t_ & 3, nt = (t_ >> 2) & 15, br = t_ >> 6;
            W = br ? fc21_w : fc11_w;
            k0 = ks * 32 + q * 8; n = nt * 16 + m;
        } else {                              // G2
            int t_ = (e - 8192) >> 6;
            int ks = t_ & 7, nt = (t_ >> 3) & 15, br = t_ >> 7;
            W = br ? W_ih2 : W_ih1;
            k0 = ks * 32 + q * 8; n = nt * 16 + m;
        }
        bf16x8 v;
#pragma unroll
        for (int j = 0; j < 8; ++j) v[j] = f2bf(W[(size_t)(k0 + j) * 256 + n]);
        ((bf16x8*)tab)[e] = v;
    } else {                                  // G3: W_hh f16 frags
        int e3 = e - 24576;
        int t_ = e3 >> 6;
        int ks = t_ & 7, nt = (t_ >> 3) & 15, brr = t_ >> 7;
        const float* W = brr ? W_hh2 : W_hh1;
        int k0 = ks * 32 + q * 8, n = nt * 16 + m;
        f16x8 v;
#pragma unroll
        for (int j = 0; j < 8; ++j) v[j] = (_Float16)W[(size_t)(k0 + j) * 256 + n];
        ((f16x8*)tab3)[e3] = v;
    }
}

// ---------------------------------------------------------------------------
// Kernel 1: feed-forward via MFMA (unchanged from R4, which passed).
// GEMM2 epilogue writes pre in the PERMUTED layout (8B packed stores).
// ---------------------------------------------------------------------------
__global__ __launch_bounds__(256, 2)
void ff_kernel(const float* __restrict__ state,
               const float* __restrict__ action,
               const float* __restrict__ fc11_b, const float* __restrict__ fc21_b,
               const float* __restrict__ b_hh1, const float* __restrict__ b_ih1,
               const float* __restrict__ b_hh2, const float* __restrict__ b_ih2,
               const short* __restrict__ tab,
               _Float16* __restrict__ pre_out)
{
    __shared__ short X1[128 * 264];

    const int tile = blockIdx.x % 500;
    const int br   = blockIdx.x / 500;
    const int tid  = threadIdx.x;
    const int w    = tid >> 6;
    const int lane = tid & 63;
    const int q = lane >> 4, m = lane & 15;
    const int row0 = tile * 128;

    const float* ba = br ? fc21_b : fc11_b;
    const float* bh = br ? b_hh2 : b_hh1;
    const float* bi = br ? b_ih2 : b_ih1;
    const bf16x8* tG1 = (const bf16x8*)tab + (size_t)br * 4096;
    const bf16x8* tG2 = (const bf16x8*)tab + 8192 + (size_t)br * 8192;

    float ba_v[16], bb_v[16];
#pragma unroll
    for (int nt = 0; nt < 16; ++nt) {
        int c = nt * 16 + m;
        ba_v[nt] = ba[c];
        bb_v[nt] = bh[c] + bi[c];
    }

    // GEMM1 a-frags from global X = concat(state, action)
    bf16x8 af[2][4];
#pragma unroll
    for (int mt = 0; mt < 2; ++mt) {
        const int rw = row0 + 64 * mt + 16 * w + m;
#pragma unroll
        for (int ks = 0; ks < 4; ++ks) {
            int k0 = ks * 32 + q * 8;
            const float* src = (k0 < 96) ? (state  + (size_t)rw * 96 + k0)
                                         : (action + (size_t)rw * 32 + (k0 - 96));
            float4 x0 = *(const float4*)src;
            float4 x1 = *(const float4*)(src + 4);
            bf16x8 a;
            a[0] = f2bf(x0.x); a[1] = f2bf(x0.y); a[2] = f2bf(x0.z); a[3] = f2bf(x0.w);
            a[4] = f2bf(x1.x); a[5] = f2bf(x1.y); a[6] = f2bf(x1.z); a[7] = f2bf(x1.w);
            af[mt][ks] = a;
        }
    }

    // GEMM1: X1 = relu(X @ Wa + ba)
#pragma unroll 4
    for (int nt = 0; nt < 16; ++nt) {
        bf16x8 bf[4];
#pragma unroll
        for (int ks = 0; ks < 4; ++ks) bf[ks] = tG1[(nt * 4 + ks) * 64 + lane];
#pragma unroll
        for (int mt = 0; mt < 2; ++mt) {
            f32x4 acc = {0.f, 0.f, 0.f, 0.f};
#pragma unroll
            for (int ks = 0; ks < 4; ++ks)
                acc = __builtin_amdgcn_mfma_f32_16x16x32_bf16(af[mt][ks], bf[ks], acc, 0, 0, 0);
#pragma unroll
            for (int r = 0; r < 4; ++r) {
                float v = acc[r] + ba_v[nt];
                v = v > 0.f ? v : 0.f;
                X1[(64 * mt + 16 * w + q * 4 + r) * 264 + nt * 16 + m] = f2bf(v);
            }
        }
    }

    // GEMM2 a-frags from LDS (same-wave rows, lgkmcnt suffices)
    bf16x8 a2[2][8];
#pragma unroll
    for (int mt = 0; mt < 2; ++mt)
#pragma unroll
        for (int ks = 0; ks < 8; ++ks)
            a2[mt][ks] = *(const bf16x8*)&X1[(64 * mt + 16 * w + m) * 264 + ks * 32 + q * 8];

    // permuted-store address bases per (mt, r)
    size_t hbase[2][4];
#pragma unroll
    for (int mt = 0; mt < 2; ++mt)
#pragma unroll
        for (int r = 0; r < 4; ++r) {
            unsigned row = (unsigned)(row0 + 64 * mt + 16 * w + q * 4 + r);
            unsigned b = row / 1000u;
            unsigned t = row - b * 1000u;
            unsigned G = b >> 4, g2 = (b >> 2) & 3, rr = b & 3;
            hbase[mt][r] = (size_t)(((unsigned)br * 4u + G) * 1000u + t) * 4096u
                         + (size_t)(g2 * 16 + m) * 16u + rr * 4u;
        }

    // GEMM2 grouped by target wave wv (nt = wv*4+tl), packed 8B stores
#pragma unroll
    for (int wv = 0; wv < 4; ++wv) {
        f32x4 accq[2][4];
#pragma unroll
        for (int tl = 0; tl < 4; ++tl) {
            const int nt = wv * 4 + tl;
            bf16x8 bg[8];
#pragma unroll
            for (int ks = 0; ks < 8; ++ks) bg[ks] = tG2[(nt * 8 + ks) * 64 + lane];
#pragma unroll
            for (int mt = 0; mt < 2; ++mt) {
                f32x4 acc = {0.f, 0.f, 0.f, 0.f};
#pragma unroll
                for (int ks = 0; ks < 8; ++ks)
                    acc = __builtin_amdgcn_mfma_f32_16x16x32_bf16(a2[mt][ks], bg[ks], acc, 0, 0, 0);
                accq[mt][tl] = acc;
            }
        }
#pragma unroll
        for (int mt = 0; mt < 2; ++mt)
#pragma unroll
            for (int r = 0; r < 4; ++r) {
                half2_t p0 = {(_Float16)(accq[mt][0][r] + bb_v[wv * 4 + 0]),
                              (_Float16)(accq[mt][1][r] + bb_v[wv * 4 + 1])};
                half2_t p1 = {(_Float16)(accq[mt][2][r] + bb_v[wv * 4 + 2]),
                              (_Float16)(accq[mt][3][r] + bb_v[wv * 4 + 3])};
                uint2 pk = {__builtin_bit_cast(unsigned, p0),
                            __builtin_bit_cast(unsigned, p1)};
                *(uint2*)(pre_out + hbase[mt][r] + (size_t)wv * 1024u) = pk;
            }
    }
}

// ---------------------------------------------------------------------------
// Kernel 2: MFMA recurrence, 16 seqs/block, 8 blocks x 512 thr (8 waves ->
// 2 waves/SIMD). Fixes vs R4 (2560 cy/step: 1.02M LDS-conflict cy/step +
// depth-8 MFMA chain + 1 wave/SIMD):
//  1. XOR-swizzled h tile (row_byte ^= (seq&7)<<4, pitch 512B): A-frag
//     ds_read_b128 banks become ks*16+4*(q^(m&7)) -> uniform (linear-pattern
//     statistics, ~12cy/read); was 8-16 lanes on one bank slot.
//  2. 4 independent MFMA chains of depth 4 (ks 0-3 / 4-7, 2 n-tiles).
//  3. N=32/wave: 8 sigmoids/lane (was 16); raw v_rcp for the divide.
// pre/h use R4's verified permuted layout: 4 dword loads / 4 dword stores
// per lane per step; prefetch t+2 (same parity -> no rotate copies).
// ---------------------------------------------------------------------------
__global__ __launch_bounds__(512)
__attribute__((amdgpu_waves_per_eu(2, 2)))
void rnn_kernel(const _Float16* __restrict__ pre_all,
                const float* __restrict__ hn,
                const _Float16* __restrict__ tab3,
                _Float16* __restrict__ h_out)
{
    __shared__ _Float16 hl[2][16 * 256];   // 16 KB, XOR-swizzled rows

    const int blk = blockIdx.x;            // 0..7
    const int br = blk >> 2;
    const int G  = blk & 3;
    const int tid = threadIdx.x;
    const int wv = tid >> 6, l = tid & 63;
    const int q = l >> 4, m = l & 15;

    // B-frags for this wave's 2 n-tiles (nt = wv*2+tl): 64 VGPRs
    f16x8 wfr0[8], wfr1[8];
#pragma unroll
    for (int ks = 0; ks < 8; ++ks) {
        wfr0[ks] = ((const f16x8*)tab3)[(((size_t)br * 16 + wv * 2 + 0) * 8 + ks) * 64 + l];
        wfr1[ks] = ((const f16x8*)tab3)[(((size_t)br * 16 + wv * 2 + 1) * 8 + ks) * 64 + l];
    }
#pragma unroll
    for (int ks = 0; ks < 8; ++ks) {
        __asm__ __volatile__("" : "+v"(wfr0[ks]));
        __asm__ __volatile__("" : "+v"(wfr1[ks]));
    }

    // init hl[0] from hn (swizzled): thread covers (seq=tid>>5, 8 k-values)
    {
        const int seq = tid >> 5, kc = (tid & 31) * 8;
        const float* src = hn + (size_t)(G * 16 + seq) * 256 + kc;
        float4 x0 = *(const float4*)src;
        float4 x1 = *(const float4*)(src + 4);
        f16x8 v;
        v[0] = (_Float16)x0.x; v[1] = (_Float16)x0.y; v[2] = (_Float16)x0.z; v[3] = (_Float16)x0.w;
        v[4] = (_Float16)x1.x; v[5] = (_Float16)x1.y; v[6] = (_Float16)x1.z; v[7] = (_Float16)x1.w;
        const int rb = (kc * 2) ^ ((seq & 7) << 4);
        *(f16x8*)((char*)&hl[0][0] + seq * 512 + rb) = v;
    }
    barrier_lds();

    // per-lane half-offset into a slab (R4 permuted layout; tl2 pair = dword)
    const int lb = ((wv >> 1) << 10) + (q << 8) + (m << 4) + ((wv & 1) << 1);
    const size_t slab0 = (size_t)(br * 4 + G) * 1000u;
    const _Float16* preB = pre_all + slab0 * 4096u + lb;
    _Float16* hgB = h_out + slab0 * 4096u + lb;

    unsigned pA[4], pB[4];
#pragma unroll
    for (int r = 0; r < 4; ++r) pA[r] = *(const unsigned*)(preB + (size_t)r * 4u);
#pragma unroll
    for (int r = 0; r < 4; ++r) pB[r] = *(const unsigned*)(preB + 4096u + (size_t)r * 4u);

#define RSTEP(P, PR, TT)                                                      \
    {                                                                         \
        const int t2 = ((TT) + 2 < 1000) ? ((TT) + 2) : 999;                  \
        const _Float16* pT2 = preB + (size_t)t2 * 4096u;                      \
        unsigned p2_[4];                                                      \
        _Pragma("unroll")                                                     \
        for (int r = 0; r < 4; ++r) p2_[r] = *(const unsigned*)(pT2 + r * 4); \
        /* A-frags from swizzled hl[P] */                                     \
        f16x8 a_[8];                                                          \
        _Pragma("unroll")                                                     \
        for (int ks = 0; ks < 8; ++ks) {                                      \
            const int rb = ((ks * 64 + q * 16) ^ ((m & 7) << 4));             \
            a_[ks] = *(const f16x8*)((const char*)&hl[P][0] + m * 512 + rb);  \
        }                                                                     \
        f32x4 aA0, aA1, aB0, aB1;                                             \
        _Pragma("unroll")                                                     \
        for (int r = 0; r < 4; ++r) {                                         \
            half2_t ph = __builtin_bit_cast(half2_t, PR[r]);                  \
            aA0[r] = (float)ph[0];                                            \
            aA1[r] = (float)ph[1];                                            \
            aB0[r] = 0.f; aB1[r] = 0.f;                                       \
        }                                                                     \
        _Pragma("unroll")                                                     \
        for (int ks = 0; ks < 4; ++ks) {                                      \
            aA0 = __builtin_amdgcn_mfma_f32_16x16x32_f16(a_[ks], wfr0[ks], aA0, 0, 0, 0); \
            aA1 = __builtin_amdgcn_mfma_f32_16x16x32_f16(a_[ks], wfr1[ks], aA1, 0, 0, 0); \
        }                                                                     \
        _Pragma("unroll")                                                     \
        for (int ks = 4; ks < 8; ++ks) {                                      \
            aB0 = __builtin_amdgcn_mfma_f32_16x16x32_f16(a_[ks], wfr0[ks], aB0, 0, 0, 0); \
            aB1 = __builtin_amdgcn_mfma_f32_16x16x32_f16(a_[ks], wfr1[ks], aB1, 0, 0, 0); \
        }                                                                     \
        _Float16* hgT = hgB + (size_t)(TT) * 4096u;                           \
        char* wbase = (char*)&hl[(P) ^ 1][0];                                 \
        _Pragma("unroll")                                                     \
        for (int r = 0; r < 4; ++r) {                                         \
            const float z0 = aA0[r] + aB0[r];                                 \
            const float z1 = aA1[r] + aB1[r];                                 \
            const float h0 = __builtin_amdgcn_rcpf(1.0f + __expf(-z0));       \
            const float h1 = __builtin_amdgcn_rcpf(1.0f + __expf(-z1));       \
            half2_t hh = {(_Float16)h0, (_Float16)h1};                        \
            *(unsigned*)(hgT + r * 4) = __builtin_bit_cast(unsigned, hh);     \
            const int seq = q * 4 + r;                                        \
            char* rp = wbase + seq * 512;                                     \
            const int swz = (seq & 7) << 4;                                   \
            *(_Float16*)(rp + ((wv * 64 + m * 2) ^ swz))      = hh[0];        \
            *(_Float16*)(rp + ((wv * 64 + 32 + m * 2) ^ swz)) = hh[1];        \
            PR[r] = p2_[r];                                                   \
        }                                                                     \
        barrier_lds();                                                        \
    }

    for (int tt = 0; tt < 1000; tt += 2) {
        RSTEP(0, pA, tt)
        RSTEP(1, pB, tt + 1)
    }
#undef RSTEP
}

// ---------------------------------------------------------------------------
// Kernel 3: q head on permuted h (unchanged from R4, which passed).
// ---------------------------------------------------------------------------
__global__ __launch_bounds__(256, 4)
void q_kernel(const _Float16* __restrict__ h_all,
              const float* __restrict__ fc12_w, const float* __restrict__ fc12_b,
              const float* __restrict__ fc22_w, const float* __restrict__ fc22_b,
              float* __restrict__ out)
{
    __shared__ float part[4][4][4];       // [wv][g2][r]
    const int sb  = blockIdx.x;           // slab = (br*4+G)*1000 + t, 8000 blocks
    const int br  = sb / 4000;
    const int rem = sb - br * 4000;
    const int G   = rem / 1000;
    const int t   = rem - G * 1000;
    const int tid = threadIdx.x;
    const int wv = tid >> 6, l = tid & 63, g2 = l >> 4, m = l & 15;
    const float* qwp = br ? fc22_w : fc12_w;

    f16x16 hv = *(const f16x16*)(h_all + (size_t)sb * 4096u + (size_t)tid * 16u);
    half2_t q01 = {(_Float16)qwp[wv * 64 + 0 * 16 + m], (_Float16)qwp[wv * 64 + 1 * 16 + m]};
    half2_t q23 = {(_Float16)qwp[wv * 64 + 2 * 16 + m], (_Float16)qwp[wv * 64 + 3 * 16 + m]};

    float s0, s1, s2, s3;
    {
        half2_t a0 = {hv[0],  hv[1]},  b0 = {hv[2],  hv[3]};
        half2_t a1 = {hv[4],  hv[5]},  b1 = {hv[6],  hv[7]};
        half2_t a2 = {hv[8],  hv[9]},  b2 = {hv[10], hv[11]};
        half2_t a3 = {hv[12], hv[13]}, b3 = {hv[14], hv[15]};
        s0 = fdot2(b0, q23, fdot2(a0, q01, 0.f));
        s1 = fdot2(b1, q23, fdot2(a1, q01, 0.f));
        s2 = fdot2(b2, q23, fdot2(a2, q01, 0.f));
        s3 = fdot2(b3, q23, fdot2(a3, q01, 0.f));
    }
#pragma unroll
    for (int off = 1; off < 16; off <<= 1) {
        s0 += __shfl_xor(s0, off, 64);
        s1 += __shfl_xor(s1, off, 64);
        s2 += __shfl_xor(s2, off, 64);
        s3 += __shfl_xor(s3, off, 64);
    }
    if (m == 0) *(float4*)&part[wv][g2][0] = float4{s0, s1, s2, s3};
    __syncthreads();
    if (tid < 16) {
        const int gg = tid >> 2, rr = tid & 3;
        float q_ = (part[0][gg][rr] + part[1][gg][rr]) +
                   (part[2][gg][rr] + part[3][gg][rr]) +
                   (br ? fc22_b[0] : fc12_b[0]);
        out[(size_t)br * 64000u + (size_t)(G * 16 + gg * 4 + rr) * 1000u + t] = q_;
    }
}

// ---------------------------------------------------------------------------
extern "C" void kernel_launch(void* const* d_in, const int* in_sizes, int n_in,
                              void* d_out, int out_size, void* d_ws, size_t ws_size,
                              hipStream_t stream)
{
    const float* state  = (const float*)d_in[0];
    const float* action = (const float*)d_in[1];
    const float* hn     = (const float*)d_in[2];
    const float* fc11_w = (const float*)d_in[3];
    const float* fc11_b = (const float*)d_in[4];
    const float* W_hh1  = (const float*)d_in[5];
    const float* W_ih1  = (const float*)d_in[6];
    const float* b_hh1  = (const float*)d_in[7];
    const float* b_ih1  = (const float*)d_in[8];
    const float* fc12_w = (const float*)d_in[9];
    const float* fc12_b = (const float*)d_in[10];
    const float* fc21_w = (const float*)d_in[11];
    const float* fc21_b = (const float*)d_in[12];
    const float* W_hh2  = (const float*)d_in[13];
    const float* W_ih2  = (const float*)d_in[14];
    const float* b_hh2  = (const float*)d_in[15];
    const float* b_ih2  = (const float*)d_in[16];
    const float* fc22_w = (const float*)d_in[17];
    const float* fc22_b = (const float*)d_in[18];

    _Float16* pre  = (_Float16*)d_ws;                          // 65,536,000 B
    _Float16* hbg  = (_Float16*)d_ws + 32768000u;              // 65,536,000 B
    _Float16* tab3 = (_Float16*)((char*)d_ws + 130416640u);    // 262,144 B (h tail)
    short*    tab  = (short*)((char*)d_ws + 130678784u);       // 393,216 B (h tail)

    prep_kernel<<<160, 256, 0, stream>>>(fc11_w, W_ih1, fc21_w, W_ih2,
                                         W_hh1, W_hh2, tab, tab3);
    ff_kernel<<<1000, 256, 0, stream>>>(state, action,
                                        fc11_b, fc21_b, b_hh1, b_ih1,
                                        b_hh2, b_ih2, tab, pre);
    rnn_kernel<<<8, 512, 0, stream>>>(pre, hn, tab3, hbg);
    q_kernel<<<8000, 256, 0, stream>>>(hbg, fc12_w, fc12_b, fc22_w, fc22_b,
                                       (float*)d_out);
}

// Round 7
// 1777.913 us; speedup vs baseline: 1.0001x; 1.0001x over previous
//
#include <hip/hip_runtime.h>
#include <math.h>

// B=64, T=1000, S=96, A=32, INP=128, H=256. All I/O fp32.
// d_ws layout:
//   pre_perm fp16 [8000 slabs][4096 halves] = 65,536,000 B   (slab=(br*4+G)*1000+t)
//   h_perm   fp16 same layout              = 65,536,000 B
//   G3 f16 W_hh B-frag table (262,144 B) at d_ws+130,416,640  (tail of h region)
//   G1/G2 bf16 frag tables  (393,216 B) at d_ws+130,678,784  (tail of h region)
// Tail tables are consumed at ff/rnn START; rnn's h writes only reach those
// bytes at t>=920 of slab-group (br=1,G=3) — hundreds of µs later.
// Permuted value layout (verified R4/R6 pass): value (br,b,t,col) with
//   G=b>>4, g2=(b>>2)&3, rr=b&3, WV=col>>6, TL=(col>>4)&3, mm=col&15 lives at
//   half-index slab*4096 + WV*1024 + g2*256 + mm*16 + rr*4 + TL.

typedef _Float16 half2_t __attribute__((ext_vector_type(2)));
typedef _Float16 f16x8   __attribute__((ext_vector_type(8)));    // 4 VGPRs
typedef _Float16 f16x16  __attribute__((ext_vector_type(16)));   // 8 VGPRs
typedef __attribute__((ext_vector_type(8))) short bf16x8;
typedef __attribute__((ext_vector_type(4))) float f32x4;

__device__ __forceinline__ float fdot2(half2_t a, half2_t b, float c) {
#if __has_builtin(__builtin_amdgcn_fdot2)
    return __builtin_amdgcn_fdot2(a, b, c, false);
#else
    return c + (float)a[0] * (float)b[0] + (float)a[1] * (float)b[1];
#endif
}

__device__ __forceinline__ short f2bf(float f) {     // fp32 -> bf16 (RNE)
    unsigned u = __builtin_bit_cast(unsigned, f);
    return (short)((u + 0x7FFFu + ((u >> 16) & 1u)) >> 16);
}

__device__ __forceinline__ void barrier_lds() {
    __asm__ __volatile__("s_waitcnt lgkmcnt(0)" ::: "memory");
    __builtin_amdgcn_s_barrier();
}

// ---------------------------------------------------------------------------
// Kernel 0: pre-swizzle weights into MFMA B-fragment tables.
// G1 (bf16, ff GEMM1): e in [0,8192)
// G2 (bf16, ff GEMM2): e in [8192,24576)
// G3 (f16, rnn W_hh) : e in [24576,40960): ((br*16+nt)*8+ks)*64+lane
// ---------------------------------------------------------------------------
__global__ __launch_bounds__(256, 1)
void prep_kernel(const float* __restrict__ fc11_w, const float* __restrict__ W_ih1,
                 const float* __restrict__ fc21_w, const float* __restrict__ W_ih2,
                 const float* __restrict__ W_hh1, const float* __restrict__ W_hh2,
                 short* __restrict__ tab, _Float16* __restrict__ tab3)
{
    const int e    = blockIdx.x * 256 + threadIdx.x;   // 160*256 = 40960
    const int lane = e & 63;
    const int q = lane >> 4, m = lane & 15;
    if (e < 24576) {
        const float* W;
        int k0, n;
        if (e < 8192) {                       // G1
            int t_ = e >> 6;
            int ks = t_ & 3, nt = (t_ >> 2) & 15, br = t_ >> 6;
            W = br ? fc21_w : fc11_w;
            k0 = ks * 32 + q * 8; n = nt * 16 + m;
        } else {                              // G2
            int t_ = (e - 8192) >> 6;
            int ks = t_ & 7, nt = (t_ >> 3) & 15, br = t_ >> 7;
            W = br ? W_ih2 : W_ih1;
            k0 = ks * 32 + q * 8; n = nt * 16 + m;
        }
        bf16x8 v;
#pragma unroll
        for (int j = 0; j < 8; ++j) v[j] = f2bf(W[(size_t)(k0 + j) * 256 + n]);
        ((bf16x8*)tab)[e] = v;
    } else {                                  // G3: W_hh f16 frags
        int e3 = e - 24576;
        int t_ = e3 >> 6;
        int ks = t_ & 7, nt = (t_ >> 3) & 15, brr = t_ >> 7;
        const float* W = brr ? W_hh2 : W_hh1;
        int k0 = ks * 32 + q * 8, n = nt * 16 + m;
        f16x8 v;
#pragma unroll
        for (int j = 0; j < 8; ++j) v[j] = (_Float16)W[(size_t)(k0 + j) * 256 + n];
        ((f16x8*)tab3)[e3] = v;
    }
}

// ---------------------------------------------------------------------------
// Kernel 1: feed-forward via MFMA (unchanged from R4, which passed).
// GEMM2 epilogue writes pre in the PERMUTED layout (8B packed stores).
// ---------------------------------------------------------------------------
__global__ __launch_bounds__(256, 2)
void ff_kernel(const float* __restrict__ state,
               const float* __restrict__ action,
               const float* __restrict__ fc11_b, const float* __restrict__ fc21_b,
               const float* __restrict__ b_hh1, const float* __restrict__ b_ih1,
               const float* __restrict__ b_hh2, const float* __restrict__ b_ih2,
               const short* __restrict__ tab,
               _Float16* __restrict__ pre_out)
{
    __shared__ short X1[128 * 264];

    const int tile = blockIdx.x % 500;
    const int br   = blockIdx.x / 500;
    const int tid  = threadIdx.x;
    const int w    = tid >> 6;
    const int lane = tid & 63;
    const int q = lane >> 4, m = lane & 15;
    const int row0 = tile * 128;

    const float* ba = br ? fc21_b : fc11_b;
    const float* bh = br ? b_hh2 : b_hh1;
    const float* bi = br ? b_ih2 : b_ih1;
    const bf16x8* tG1 = (const bf16x8*)tab + (size_t)br * 4096;
    const bf16x8* tG2 = (const bf16x8*)tab + 8192 + (size_t)br * 8192;

    float ba_v[16], bb_v[16];
#pragma unroll
    for (int nt = 0; nt < 16; ++nt) {
        int c = nt * 16 + m;
        ba_v[nt] = ba[c];
        bb_v[nt] = bh[c] + bi[c];
    }

    // GEMM1 a-frags from global X = concat(state, action)
    bf16x8 af[2][4];
#pragma unroll
    for (int mt = 0; mt < 2; ++mt) {
        const int rw = row0 + 64 * mt + 16 * w + m;
#pragma unroll
        for (int ks = 0; ks < 4; ++ks) {
            int k0 = ks * 32 + q * 8;
            const float* src = (k0 < 96) ? (state  + (size_t)rw * 96 + k0)
                                         : (action + (size_t)rw * 32 + (k0 - 96));
            float4 x0 = *(const float4*)src;
            float4 x1 = *(const float4*)(src + 4);
            bf16x8 a;
            a[0] = f2bf(x0.x); a[1] = f2bf(x0.y); a[2] = f2bf(x0.z); a[3] = f2bf(x0.w);
            a[4] = f2bf(x1.x); a[5] = f2bf(x1.y); a[6] = f2bf(x1.z); a[7] = f2bf(x1.w);
            af[mt][ks] = a;
        }
    }

    // GEMM1: X1 = relu(X @ Wa + ba)
#pragma unroll 4
    for (int nt = 0; nt < 16; ++nt) {
        bf16x8 bf[4];
#pragma unroll
        for (int ks = 0; ks < 4; ++ks) bf[ks] = tG1[(nt * 4 + ks) * 64 + lane];
#pragma unroll
        for (int mt = 0; mt < 2; ++mt) {
            f32x4 acc = {0.f, 0.f, 0.f, 0.f};
#pragma unroll
            for (int ks = 0; ks < 4; ++ks)
                acc = __builtin_amdgcn_mfma_f32_16x16x32_bf16(af[mt][ks], bf[ks], acc, 0, 0, 0);
#pragma unroll
            for (int r = 0; r < 4; ++r) {
                float v = acc[r] + ba_v[nt];
                v = v > 0.f ? v : 0.f;
                X1[(64 * mt + 16 * w + q * 4 + r) * 264 + nt * 16 + m] = f2bf(v);
            }
        }
    }

    // GEMM2 a-frags from LDS (same-wave rows, lgkmcnt suffices)
    bf16x8 a2[2][8];
#pragma unroll
    for (int mt = 0; mt < 2; ++mt)
#pragma unroll
        for (int ks = 0; ks < 8; ++ks)
            a2[mt][ks] = *(const bf16x8*)&X1[(64 * mt + 16 * w + m) * 264 + ks * 32 + q * 8];

    // permuted-store address bases per (mt, r)
    size_t hbase[2][4];
#pragma unroll
    for (int mt = 0; mt < 2; ++mt)
#pragma unroll
        for (int r = 0; r < 4; ++r) {
            unsigned row = (unsigned)(row0 + 64 * mt + 16 * w + q * 4 + r);
            unsigned b = row / 1000u;
            unsigned t = row - b * 1000u;
            unsigned G = b >> 4, g2 = (b >> 2) & 3, rr = b & 3;
            hbase[mt][r] = (size_t)(((unsigned)br * 4u + G) * 1000u + t) * 4096u
                         + (size_t)(g2 * 16 + m) * 16u + rr * 4u;
        }

    // GEMM2 grouped by target wave wv (nt = wv*4+tl), packed 8B stores
#pragma unroll
    for (int wv = 0; wv < 4; ++wv) {
        f32x4 accq[2][4];
#pragma unroll
        for (int tl = 0; tl < 4; ++tl) {
            const int nt = wv * 4 + tl;
            bf16x8 bg[8];
#pragma unroll
            for (int ks = 0; ks < 8; ++ks) bg[ks] = tG2[(nt * 8 + ks) * 64 + lane];
#pragma unroll
            for (int mt = 0; mt < 2; ++mt) {
                f32x4 acc = {0.f, 0.f, 0.f, 0.f};
#pragma unroll
                for (int ks = 0; ks < 8; ++ks)
                    acc = __builtin_amdgcn_mfma_f32_16x16x32_bf16(a2[mt][ks], bg[ks], acc, 0, 0, 0);
                accq[mt][tl] = acc;
            }
        }
#pragma unroll
        for (int mt = 0; mt < 2; ++mt)
#pragma unroll
            for (int r = 0; r < 4; ++r) {
                half2_t p0 = {(_Float16)(accq[mt][0][r] + bb_v[wv * 4 + 0]),
                              (_Float16)(accq[mt][1][r] + bb_v[wv * 4 + 1])};
                half2_t p1 = {(_Float16)(accq[mt][2][r] + bb_v[wv * 4 + 2]),
                              (_Float16)(accq[mt][3][r] + bb_v[wv * 4 + 3])};
                uint2 pk = {__builtin_bit_cast(unsigned, p0),
                            __builtin_bit_cast(unsigned, p1)};
                *(uint2*)(pre_out + hbase[mt][r] + (size_t)wv * 1024u) = pk;
            }
    }
}

// ---------------------------------------------------------------------------
// Kernel 2: MFMA recurrence, 16 seqs/block, 8 blocks x 512 thr (8 waves ->
// 2 waves/SIMD, sibling waves fill latency). FIX vs R6 (VGPR=88 = weight
// frags spilled to scratch, ~16 L2-latency reloads/step on the critical
// path): the "+v" asm pins on 4-register f16x8 tuples are DELETED — they
// wrecked allocation in both R4 (VGPR=136<needed) and R6 (88). MFMA reads
// B-operands directly from AGPRs, so wherever the allocator parks wfr is
// fine as long as it's not scratch. Live set ~144 regs < 256 cap at
// waves_per_eu(2,2). hl layout reverted to R4's LINEAR [2][16][264]
// (correctness-verified; R4's conflicts were only ~128cy/step = LDS BW
// floor, never the bottleneck). Split MFMA chains (depth 4+4) and rcp
// sigmoid kept from R6 (both numerically verified, absmax 0.0078125).
// ---------------------------------------------------------------------------
__global__ __launch_bounds__(512)
__attribute__((amdgpu_waves_per_eu(2, 2)))
void rnn_kernel(const _Float16* __restrict__ pre_all,
                const float* __restrict__ hn,
                const _Float16* __restrict__ tab3,
                _Float16* __restrict__ h_out)
{
    __shared__ _Float16 hl[2][16][264];    // linear, 16.9 KB

    const int blk = blockIdx.x;            // 0..7
    const int br = blk >> 2;
    const int G  = blk & 3;
    const int tid = threadIdx.x;
    const int wv = tid >> 6, l = tid & 63;
    const int q = l >> 4, m = l & 15;

    // B-frags for this wave's 2 n-tiles (nt = wv*2+tl): 64 regs, NO pins.
    f16x8 wfr0[8], wfr1[8];
#pragma unroll
    for (int ks = 0; ks < 8; ++ks) {
        wfr0[ks] = ((const f16x8*)tab3)[(((size_t)br * 16 + wv * 2 + 0) * 8 + ks) * 64 + l];
        wfr1[ks] = ((const f16x8*)tab3)[(((size_t)br * 16 + wv * 2 + 1) * 8 + ks) * 64 + l];
    }

    // init hl[0]: thread covers (seq = tid>>5, 8 k-values at (tid&31)*8)
    {
        const int seq = tid >> 5, kc = (tid & 31) * 8;
        const float* src = hn + (size_t)(G * 16 + seq) * 256 + kc;
        float4 x0 = *(const float4*)src;
        float4 x1 = *(const float4*)(src + 4);
        f16x8 v;
        v[0] = (_Float16)x0.x; v[1] = (_Float16)x0.y; v[2] = (_Float16)x0.z; v[3] = (_Float16)x0.w;
        v[4] = (_Float16)x1.x; v[5] = (_Float16)x1.y; v[6] = (_Float16)x1.z; v[7] = (_Float16)x1.w;
        *(f16x8*)&hl[0][seq][kc] = v;
    }
    barrier_lds();

    // per-lane half-offset into a slab (verified permuted layout):
    // this lane owns seqs s=q*4+r, cols wv*32 + tl*16 + m (tl=0,1)
    const int lb = ((wv >> 1) << 10) + (q << 8) + (m << 4) + ((wv & 1) << 1);
    const size_t slab0 = (size_t)(br * 4 + G) * 1000u;
    const _Float16* preB = pre_all + slab0 * 4096u + lb;
    _Float16* hgB = h_out + slab0 * 4096u + lb;

    unsigned pA[4], pB[4];
#pragma unroll
    for (int r = 0; r < 4; ++r) pA[r] = *(const unsigned*)(preB + (size_t)r * 4u);
#pragma unroll
    for (int r = 0; r < 4; ++r) pB[r] = *(const unsigned*)(preB + 4096u + (size_t)r * 4u);

#define RSTEP(P, PR, TT)                                                      \
    {                                                                         \
        const int t2 = ((TT) + 2 < 1000) ? ((TT) + 2) : 999;                  \
        const _Float16* pT2 = preB + (size_t)t2 * 4096u;                      \
        unsigned p2_[4];                                                      \
        _Pragma("unroll")                                                     \
        for (int r = 0; r < 4; ++r) p2_[r] = *(const unsigned*)(pT2 + r * 4); \
        /* A-frags: lane reads hl[seq=m][k = ks*32 + q*8 .. +8] */            \
        f16x8 a_[8];                                                          \
        _Pragma("unroll")                                                     \
        for (int ks = 0; ks < 8; ++ks)                                        \
            a_[ks] = *(const f16x8*)&hl[P][m][ks * 32 + q * 8];               \
        f32x4 aA0, aA1, aB0, aB1;                                             \
        _Pragma("unroll")                                                     \
        for (int r = 0; r < 4; ++r) {                                         \
            half2_t ph = __builtin_bit_cast(half2_t, PR[r]);                  \
            aA0[r] = (float)ph[0];                                            \
            aA1[r] = (float)ph[1];                                            \
            aB0[r] = 0.f; aB1[r] = 0.f;                                       \
        }                                                                     \
        _Pragma("unroll")                                                     \
        for (int ks = 0; ks < 4; ++ks) {                                      \
            aA0 = __builtin_amdgcn_mfma_f32_16x16x32_f16(a_[ks], wfr0[ks], aA0, 0, 0, 0); \
            aA1 = __builtin_amdgcn_mfma_f32_16x16x32_f16(a_[ks], wfr1[ks], aA1, 0, 0, 0); \
        }                                                                     \
        _Pragma("unroll")                                                     \
        for (int ks = 4; ks < 8; ++ks) {                                      \
            aB0 = __builtin_amdgcn_mfma_f32_16x16x32_f16(a_[ks], wfr0[ks], aB0, 0, 0, 0); \
            aB1 = __builtin_amdgcn_mfma_f32_16x16x32_f16(a_[ks], wfr1[ks], aB1, 0, 0, 0); \
        }                                                                     \
        _Float16* hgT = hgB + (size_t)(TT) * 4096u;                           \
        _Pragma("unroll")                                                     \
        for (int r = 0; r < 4; ++r) {                                         \
            const float z0 = aA0[r] + aB0[r];                                 \
            const float z1 = aA1[r] + aB1[r];                                 \
            const float h0 = __builtin_amdgcn_rcpf(1.0f + __expf(-z0));       \
            const float h1 = __builtin_amdgcn_rcpf(1.0f + __expf(-z1));       \
            half2_t hh = {(_Float16)h0, (_Float16)h1};                        \
            *(unsigned*)(hgT + r * 4) = __builtin_bit_cast(unsigned, hh);     \
            const int seq = q * 4 + r;                                        \
            hl[(P) ^ 1][seq][wv * 32 + m]      = hh[0];                       \
            hl[(P) ^ 1][seq][wv * 32 + 16 + m] = hh[1];                       \
            PR[r] = p2_[r];                                                   \
        }                                                                     \
        barrier_lds();                                                        \
    }

    for (int tt = 0; tt < 1000; tt += 2) {
        RSTEP(0, pA, tt)
        RSTEP(1, pB, tt + 1)
    }
#undef RSTEP
}

// ---------------------------------------------------------------------------
// Kernel 3: q head on permuted h (unchanged from R4, which passed).
// ---------------------------------------------------------------------------
__global__ __launch_bounds__(256, 4)
void q_kernel(const _Float16* __restrict__ h_all,
              const float* __restrict__ fc12_w, const float* __restrict__ fc12_b,
              const float* __restrict__ fc22_w, const float* __restrict__ fc22_b,
              float* __restrict__ out)
{
    __shared__ float part[4][4][4];       // [wv][g2][r]
    const int sb  = blockIdx.x;           // slab = (br*4+G)*1000 + t, 8000 blocks
    const int br  = sb / 4000;
    const int rem = sb - br * 4000;
    const int G   = rem / 1000;
    const int t   = rem - G * 1000;
    const int tid = threadIdx.x;
    const int wv = tid >> 6, l = tid & 63, g2 = l >> 4, m = l & 15;
    const float* qwp = br ? fc22_w : fc12_w;

    f16x16 hv = *(const f16x16*)(h_all + (size_t)sb * 4096u + (size_t)tid * 16u);
    half2_t q01 = {(_Float16)qwp[wv * 64 + 0 * 16 + m], (_Float16)qwp[wv * 64 + 1 * 16 + m]};
    half2_t q23 = {(_Float16)qwp[wv * 64 + 2 * 16 + m], (_Float16)qwp[wv * 64 + 3 * 16 + m]};

    float s0, s1, s2, s3;
    {
        half2_t a0 = {hv[0],  hv[1]},  b0 = {hv[2],  hv[3]};
        half2_t a1 = {hv[4],  hv[5]},  b1 = {hv[6],  hv[7]};
        half2_t a2 = {hv[8],  hv[9]},  b2 = {hv[10], hv[11]};
        half2_t a3 = {hv[12], hv[13]}, b3 = {hv[14], hv[15]};
        s0 = fdot2(b0, q23, fdot2(a0, q01, 0.f));
        s1 = fdot2(b1, q23, fdot2(a1, q01, 0.f));
        s2 = fdot2(b2, q23, fdot2(a2, q01, 0.f));
        s3 = fdot2(b3, q23, fdot2(a3, q01, 0.f));
    }
#pragma unroll
    for (int off = 1; off < 16; off <<= 1) {
        s0 += __shfl_xor(s0, off, 64);
        s1 += __shfl_xor(s1, off, 64);
        s2 += __shfl_xor(s2, off, 64);
        s3 += __shfl_xor(s3, off, 64);
    }
    if (m == 0) *(float4*)&part[wv][g2][0] = float4{s0, s1, s2, s3};
    __syncthreads();
    if (tid < 16) {
        const int gg = tid >> 2, rr = tid & 3;
        float q_ = (part[0][gg][rr] + part[1][gg][rr]) +
                   (part[2][gg][rr] + part[3][gg][rr]) +
                   (br ? fc22_b[0] : fc12_b[0]);
        out[(size_t)br * 64000u + (size_t)(G * 16 + gg * 4 + rr) * 1000u + t] = q_;
    }
}

// ---------------------------------------------------------------------------
extern "C" void kernel_launch(void* const* d_in, const int* in_sizes, int n_in,
                              void* d_out, int out_size, void* d_ws, size_t ws_size,
                              hipStream_t stream)
{
    const float* state  = (const float*)d_in[0];
    const float* action = (const float*)d_in[1];
    const float* hn     = (const float*)d_in[2];
    const float* fc11_w = (const float*)d_in[3];
    const float* fc11_b = (const float*)d_in[4];
    const float* W_hh1  = (const float*)d_in[5];
    const float* W_ih1  = (const float*)d_in[6];
    const float* b_hh1  = (const float*)d_in[7];
    const float* b_ih1  = (const float*)d_in[8];
    const float* fc12_w = (const float*)d_in[9];
    const float* fc12_b = (const float*)d_in[10];
    const float* fc21_w = (const float*)d_in[11];
    const float* fc21_b = (const float*)d_in[12];
    const float* W_hh2  = (const float*)d_in[13];
    const float* W_ih2  = (const float*)d_in[14];
    const float* b_hh2  = (const float*)d_in[15];
    const float* b_ih2  = (const float*)d_in[16];
    const float* fc22_w = (const float*)d_in[17];
    const float* fc22_b = (const float*)d_in[18];

    _Float16* pre  = (_Float16*)d_ws;                          // 65,536,000 B
    _Float16* hbg  = (_Float16*)d_ws + 32768000u;              // 65,536,000 B
    _Float16* tab3 = (_Float16*)((char*)d_ws + 130416640u);    // 262,144 B (h tail)
    short*    tab  = (short*)((char*)d_ws + 130678784u);       // 393,216 B (h tail)

    prep_kernel<<<160, 256, 0, stream>>>(fc11_w, W_ih1, fc21_w, W_ih2,
                                         W_hh1, W_hh2, tab, tab3);
    ff_kernel<<<1000, 256, 0, stream>>>(state, action,
                                        fc11_b, fc21_b, b_hh1, b_ih1,
                                        b_hh2, b_ih2, tab, pre);
    rnn_kernel<<<8, 512, 0, stream>>>(pre, hn, tab3, hbg);
    q_kernel<<<8000, 256, 0, stream>>>(hbg, fc12_w, fc12_b, fc22_w, fc22_b,
                                       (float*)d_out);
}